// Round 1
// 740.299 us; speedup vs baseline: 1.1578x; 1.1578x over previous
//
#include <hip/hip_runtime.h>

#define NN    8192
#define WSZ   256
#define KKEEP 179
#define SCALE 0.044194173824159216f   // 512^-0.5

typedef __attribute__((ext_vector_type(8))) __bf16 bf16x8;  // MFMA A/B frag (4 VGPRs)
typedef __attribute__((ext_vector_type(4))) short  s16x4;
typedef __attribute__((ext_vector_type(8))) short  s16x8;
typedef __attribute__((ext_vector_type(4))) float  f32x4;

// ---------------------------------------------------------------------------
// Dekker-style 3-way bf16 split: x ~= h + m + l  (repr. error ~2^-24 |x|).
// ---------------------------------------------------------------------------
struct Split3 { short h, m, l; };
__device__ __forceinline__ Split3 split3(float x)
{
    unsigned u  = __float_as_uint(x);
    unsigned hb = ((u + 0x7FFFu + ((u >> 16) & 1u)) >> 16) << 16;
    float r = x - __uint_as_float(hb);
    unsigned ur = __float_as_uint(r);
    unsigned mb = ((ur + 0x7FFFu + ((ur >> 16) & 1u)) >> 16) << 16;
    float r2 = r - __uint_as_float(mb);
    unsigned lr = __float_as_uint(r2);
    unsigned lb = (lr + 0x7FFFu + ((lr >> 16) & 1u)) >> 16;
    Split3 s;
    s.h = (short)(hb >> 16);
    s.m = (short)(mb >> 16);
    s.l = (short)(lb & 0xFFFFu);
    return s;
}

// 2-way split: x ~= h + m  (error ~2^-18 |x|) — for P (post-softmax) and V.
__device__ __forceinline__ void split2(float x, short& h, short& m)
{
    unsigned u  = __float_as_uint(x);
    unsigned hb = ((u + 0x7FFFu + ((u >> 16) & 1u)) >> 16) << 16;
    float r = x - __uint_as_float(hb);
    unsigned ur = __float_as_uint(r);
    unsigned mb = (ur + 0x7FFFu + ((ur >> 16) & 1u)) >> 16;
    h = (short)(hb >> 16);
    m = (short)(mb & 0xFFFFu);
}

// ---------------------------------------------------------------------------
// Pre-split + transpose a weight matrix W[K][N] fp32 -> h/m/l [N][K] bf16.
// ---------------------------------------------------------------------------
__global__ __launch_bounds__(256) void splitw_kernel(const float* __restrict__ W,
                                                     int K, int N,
                                                     short* __restrict__ h,
                                                     short* __restrict__ m,
                                                     short* __restrict__ l)
{
    int idx = blockIdx.x * 256 + threadIdx.x;
    if (idx >= K * N) return;
    int k = idx / N, n = idx - k * N;
    Split3 s = split3(W[idx]);
    size_t o = (size_t)n * K + k;
    h[o] = s.h; m[o] = s.m; l[o] = s.l;
}

// ---------------------------------------------------------------------------
// MFMA GEMM: C[M,N] = A[M,K=512] @ B[K,N] (+bias)  (unchanged)
// ---------------------------------------------------------------------------
__global__ __launch_bounds__(256, 2) void gemm_mfma(const float* __restrict__ A, int lda,
                                                    const short* __restrict__ BTh,
                                                    const short* __restrict__ BTm,
                                                    const short* __restrict__ BTl,
                                                    const float* __restrict__ bias,
                                                    float* __restrict__ C, int ldc,
                                                    int qk_cols)
{
    __shared__ __align__(16) short Asm[3][128 * 40];   // [split][m][k] bf16
    __shared__ __align__(16) short Bsm[3][128 * 40];   // [split][n][k] bf16

    const int t       = threadIdx.x;
    const int lane    = t & 63;
    const int wave    = t >> 6;
    const int wr      = wave >> 1;
    const int wc      = wave & 1;
    const int rowBase = blockIdx.y * 128;
    const int colBase = blockIdx.x * 128;
    const int pstart  = (colBase < qk_cols) ? 0 : 3;

    const int sa[6] = {2, 0, 1, 1, 0, 0};
    const int sb[6] = {0, 2, 1, 0, 1, 0};

    const int fn = lane & 15;
    const int fq = (lane >> 4) * 8;

    f32x4 acc[4][4] = {};

    for (int ks = 0; ks < 512; ks += 32) {
        __syncthreads();

#pragma unroll
        for (int lo = 0; lo < 4; ++lo) {
            int idx = lo * 256 + t;
            int am  = idx >> 3;
            int af  = (idx & 7) * 4;
            float4 a4 = *(const float4*)&A[(size_t)(rowBase + am) * lda + ks + af];
            Split3 s0 = split3(a4.x);
            Split3 s1 = split3(a4.y);
            Split3 s2 = split3(a4.z);
            Split3 s3 = split3(a4.w);
            s16x4 hv, mv, lv;
            hv[0] = s0.h; hv[1] = s1.h; hv[2] = s2.h; hv[3] = s3.h;
            mv[0] = s0.m; mv[1] = s1.m; mv[2] = s2.m; mv[3] = s3.m;
            lv[0] = s0.l; lv[1] = s1.l; lv[2] = s2.l; lv[3] = s3.l;
            int o = am * 40 + af;
            *(s16x4*)&Asm[0][o] = hv;
            *(s16x4*)&Asm[1][o] = mv;
            *(s16x4*)&Asm[2][o] = lv;
        }
#pragma unroll
        for (int lo = 0; lo < 2; ++lo) {
            int c = lo * 256 + t;
            int n = c >> 2;
            int q = (c & 3) * 8;
            size_t src = (size_t)(colBase + n) * 512 + ks + q;
            int o = n * 40 + q;
            *(s16x8*)&Bsm[0][o] = *(const s16x8*)&BTh[src];
            *(s16x8*)&Bsm[1][o] = *(const s16x8*)&BTm[src];
            *(s16x8*)&Bsm[2][o] = *(const s16x8*)&BTl[src];
        }
        __syncthreads();

        bf16x8 Bf[3][4];
#pragma unroll
        for (int s = 0; s < 3; ++s)
#pragma unroll
            for (int j = 0; j < 4; ++j)
                Bf[s][j] = *(const bf16x8*)&Bsm[s][(wc * 64 + j * 16 + fn) * 40 + fq];

#pragma unroll
        for (int i = 0; i < 4; ++i) {
            bf16x8 Af[3];
#pragma unroll
            for (int s = 0; s < 3; ++s)
                Af[s] = *(const bf16x8*)&Asm[s][(wr * 64 + i * 16 + fn) * 40 + fq];
#pragma unroll
            for (int p = 0; p < 6; ++p) {
                if (p < pstart) continue;
#pragma unroll
                for (int j = 0; j < 4; ++j)
                    acc[i][j] = __builtin_amdgcn_mfma_f32_16x16x32_bf16(
                        Af[sa[p]], Bf[sb[p]][j], acc[i][j], 0, 0, 0);
            }
        }
    }

    const int crow0 = rowBase + wr * 64 + (lane >> 4) * 4;
    const int ccol0 = colBase + wc * 64 + fn;
#pragma unroll
    for (int j = 0; j < 4; ++j) {
        int col = ccol0 + j * 16;
        float bv = bias ? bias[col] : 0.0f;
#pragma unroll
        for (int i = 0; i < 4; ++i)
#pragma unroll
            for (int r = 0; r < 4; ++r)
                C[(size_t)(crow0 + i * 16 + r) * ldc + col] = acc[i][j][r] + bv;
    }
}

// ---------------------------------------------------------------------------
__global__ __launch_bounds__(256) void means_kernel(const float* __restrict__ qkv,
                                                    float* __restrict__ q_mean,
                                                    float* __restrict__ k_mean)
{
    int idx = blockIdx.x * 256 + threadIdx.x;
    int dd = idx & 63;
    int i  = (idx >> 6) & 255;
    int bh = idx >> 14;
    int b = bh >> 3, h = bh & 7;
    const float* base = qkv + (size_t)b * NN * 1536 + (size_t)h * 64 + dd;
    float qs = 0.f, ks = 0.f;
#pragma unroll
    for (int w = 0; w < 32; ++w) {
        size_t off = (size_t)(w * 256 + i) * 1536;
        qs += base[off];
        ks += base[off + 512];
    }
    q_mean[idx] = qs * 0.03125f;
    k_mean[idx] = ks * 0.03125f;
}

// ---------------------------------------------------------------------------
__global__ __launch_bounds__(256) void globalbias_kernel(const float* __restrict__ q_mean,
                                                         const float* __restrict__ k_mean,
                                                         const float* __restrict__ gp,
                                                         float* __restrict__ gbias)
{
    __shared__ float gq[32 * 64];
    const int bh = blockIdx.x;
    const int h  = bh & 7;
    const int t  = threadIdx.x;

#pragma unroll
    for (int e = 0; e < 8; ++e) {
        int idx = e * 256 + t;
        int g  = idx >> 6;
        int dd = idx & 63;
        const float* gpr = gp + (size_t)(h * 32 + g) * 256;
        const float* qm  = q_mean + (size_t)bh * 16384 + dd;
        float s = 0.f;
        for (int i = 0; i < 256; ++i) s += gpr[i] * qm[(size_t)i * 64];
        gq[idx] = s;
    }
    __syncthreads();

    const float* km = k_mean + (size_t)bh * 16384 + (size_t)t * 64;
    float4 kr[16];
#pragma unroll
    for (int j = 0; j < 16; ++j) kr[j] = *(const float4*)&km[4 * j];
    float acc = 0.f;
    for (int g = 0; g < 32; ++g) {
        const float* gqr = &gq[g * 64];
        float s = 0.f;
#pragma unroll
        for (int j = 0; j < 16; ++j) {
            float4 q4 = *(const float4*)&gqr[4 * j];
            s += q4.x * kr[j].x + q4.y * kr[j].y + q4.z * kr[j].z + q4.w * kr[j].w;
        }
        acc += s;
    }
    gbias[bh * 256 + t] = acc * SCALE * 0.03125f;
}

// ---------------------------------------------------------------------------
__device__ __forceinline__ unsigned mono_enc(float f) {
    unsigned u = __float_as_uint(f);
    return (u & 0x80000000u) ? ~u : (u | 0x80000000u);
}
__device__ __forceinline__ float mono_dec(unsigned e) {
    return (e & 0x80000000u) ? __uint_as_float(e ^ 0x80000000u)
                             : __uint_as_float(~e);
}

// ---------------------------------------------------------------------------
// Fused windowed attention, one block per (b,h,w,rc): 64 rows x 256 cols.
// QK^T: 6-product 3-limb bf16 MFMA (fp32-equivalent scores, same schedule as
// gemm_mfma). PV: 3-product 2-limb bf16 MFMA (~2^-18 rel err). Top-k bisection
// and masked softmax unchanged (same 4-thread/row layout via st).
// LDS: Qs = Q limbs [3][64][64] (XOR swizzle (row&7)<<3 on short index);
//      Ks = K limbs [3][64][64] (same swizzle); st[64][68] f32 ALIASES Ks
//      (K limbs dead after each mc's MFMAs). PV: Qs reused for P limbs [2],
//      Ks reused for V^T limbs [2][64][72] (padded, m-contiguous).
// ---------------------------------------------------------------------------
__global__ __launch_bounds__(256, 3) void attn_kernel(float* __restrict__ qkv,
                                                      const float* __restrict__ local_bias,
                                                      const float* __restrict__ gbias,
                                                      const float* __restrict__ gate)
{
    __shared__ __align__(16) short Qs[3 * 64 * 64];   // 24576 B
    __shared__ __align__(16) short Ks[3 * 64 * 64];   // 24576 B
    float* st = (float*)(void*)Ks;                    // [64][68] score tile (alias)

    const int t    = threadIdx.x;
    const int lane = t & 63;
    const int wave = t >> 6;
    const int wr   = wave >> 1;          // wave row half (0/1)
    const int wc   = wave & 1;           // wave col half (0/1)
    const int fn   = lane & 15;
    const int fq   = (lane >> 4) * 8;    // frag k offset (shorts)
    const int g4   = (lane >> 4) * 4;    // C/D row group

    const int blk = blockIdx.x;          // (((b*8+h)*32 + w)*4 + rc)
    const int rc  = blk & 3;
    const int w   = (blk >> 2) & 31;
    const int bh  = blk >> 7;
    const int h   = bh & 7;
    const int b   = bh >> 3;
    const float gateh = 1.0f / (1.0f + __expf(-gate[h]));

    const size_t tokBase = (size_t)b * NN + (size_t)w * WSZ;
    float* qb = qkv + tokBase * 1536 + h * 64;
    const float* kb = qb + 512;
    const float* vb = qb + 1024;

    const int rr = t >> 2, sub = t & 3;  // top-k row ownership (4 thr / row)

    const int sa[6] = {2, 0, 1, 1, 0, 0};
    const int sb[6] = {0, 2, 1, 0, 1, 0};

    // ---- stage Q limbs (once): [r][k] bf16, XOR-swizzled ----
#pragma unroll
    for (int l = 0; l < 4; ++l) {
        int f  = l * 256 + t;
        int r  = f >> 4;                 // 0..63
        int dg = (f & 15) * 4;           // k offset 0..60
        float4 a4 = *(const float4*)&qb[(size_t)(rc * 64 + r) * 1536 + dg];
        Split3 s0 = split3(a4.x), s1 = split3(a4.y), s2 = split3(a4.z), s3 = split3(a4.w);
        s16x4 hv, mv, lv;
        hv[0] = s0.h; hv[1] = s1.h; hv[2] = s2.h; hv[3] = s3.h;
        mv[0] = s0.m; mv[1] = s1.m; mv[2] = s2.m; mv[3] = s3.m;
        lv[0] = s0.l; lv[1] = s1.l; lv[2] = s2.l; lv[3] = s3.l;
        int o = r * 64 + (dg ^ ((r & 7) << 3));
        *(s16x4*)&Qs[o]        = hv;
        *(s16x4*)&Qs[4096 + o] = mv;
        *(s16x4*)&Qs[8192 + o] = lv;
    }

    float vals[64];
#pragma unroll
    for (int mc = 0; mc < 4; ++mc) {
        __syncthreads();                 // prev vals-read / frag reads done
        // ---- stage K limbs (this mc) ----
#pragma unroll
        for (int l = 0; l < 4; ++l) {
            int f  = l * 256 + t;
            int m  = f >> 4;
            int dg = (f & 15) * 4;
            float4 a4 = *(const float4*)&kb[(size_t)(mc * 64 + m) * 1536 + dg];
            Split3 s0 = split3(a4.x), s1 = split3(a4.y), s2 = split3(a4.z), s3 = split3(a4.w);
            s16x4 hv, mv, lv;
            hv[0] = s0.h; hv[1] = s1.h; hv[2] = s2.h; hv[3] = s3.h;
            mv[0] = s0.m; mv[1] = s1.m; mv[2] = s2.m; mv[3] = s3.m;
            lv[0] = s0.l; lv[1] = s1.l; lv[2] = s2.l; lv[3] = s3.l;
            int o = m * 64 + (dg ^ ((m & 7) << 3));
            *(s16x4*)&Ks[o]        = hv;
            *(s16x4*)&Ks[4096 + o] = mv;
            *(s16x4*)&Ks[8192 + o] = lv;
        }
        __syncthreads();

        // ---- QK^T MFMA: 6 limb products, 2x2 tiles/wave, K=64 (2 ksteps) ----
        f32x4 acc[2][2] = {};
#pragma unroll
        for (int kk = 0; kk < 2; ++kk) {
            bf16x8 Af[3][2], Bf[3][2];
#pragma unroll
            for (int s = 0; s < 3; ++s)
#pragma unroll
                for (int i = 0; i < 2; ++i) {
                    int ar = wr * 32 + i * 16 + fn;
                    int bc = wc * 32 + i * 16 + fn;
                    Af[s][i] = *(const bf16x8*)&Qs[s * 4096 + ar * 64 + ((kk * 32 + fq) ^ ((ar & 7) << 3))];
                    Bf[s][i] = *(const bf16x8*)&Ks[s * 4096 + bc * 64 + ((kk * 32 + fq) ^ ((bc & 7) << 3))];
                }
#pragma unroll
            for (int p = 0; p < 6; ++p)
#pragma unroll
                for (int i = 0; i < 2; ++i)
#pragma unroll
                    for (int j = 0; j < 2; ++j)
                        acc[i][j] = __builtin_amdgcn_mfma_f32_16x16x32_bf16(
                            Af[sa[p]][i], Bf[sb[p]][j], acc[i][j], 0, 0, 0);
        }
        __syncthreads();                 // K-frag reads done -> st may clobber Ks

        // ---- epilogue: scale + local_bias + gate*gbias -> st ----
#pragma unroll
        for (int j = 0; j < 2; ++j) {
            int cl = wc * 32 + j * 16 + fn;
            int cf = mc * 64 + cl;
            float gb = gateh * gbias[bh * 256 + cf];
#pragma unroll
            for (int i = 0; i < 2; ++i)
#pragma unroll
                for (int r = 0; r < 4; ++r) {
                    int rl = wr * 32 + i * 16 + g4 + r;
                    st[rl * 68 + cl] = acc[i][j][r] * SCALE
                        + local_bias[((size_t)h * 256 + rc * 64 + rl) * 256 + cf] + gb;
                }
        }
        __syncthreads();
#pragma unroll
        for (int j = 0; j < 16; ++j)
            vals[mc * 16 + j] = st[rr * 68 + sub + 4 * j];
    }

    // ---- top-KKEEP threshold (unchanged) ----
    float rmin = vals[0], rmax = vals[0];
#pragma unroll
    for (int j = 1; j < 64; ++j) {
        rmin = fminf(rmin, vals[j]);
        rmax = fmaxf(rmax, vals[j]);
    }
    rmin = fminf(rmin, __shfl_xor(rmin, 1)); rmin = fminf(rmin, __shfl_xor(rmin, 2));
    rmax = fmaxf(rmax, __shfl_xor(rmax, 1)); rmax = fmaxf(rmax, __shfl_xor(rmax, 2));

    float flo = rmin, fhi = rmax;
    float thr = 0.f;
    bool  done = false;
    for (int it = 0; it < 16; ++it) {
        if (__all(done ? 1 : 0)) break;
        float mf = 0.5f * (flo + fhi);
        int c = 0;
#pragma unroll
        for (int j = 0; j < 64; ++j) c += (vals[j] >= mf) ? 1 : 0;
        c += __shfl_xor(c, 1);
        c += __shfl_xor(c, 2);
        if (!done) {
            if (c == KKEEP)      { thr = mf; done = true; }
            else if (c > KKEEP)  flo = mf;
            else                 fhi = mf;
        }
    }
    if (__any(done ? 0 : 1)) {
        unsigned lo_u = mono_enc(flo), hi_u = mono_enc(fhi);
        for (int it = 0; it < 34; ++it) {
            bool active = (!done) && (lo_u < hi_u);
            if (!__any(active ? 1 : 0)) break;
            unsigned span = hi_u - lo_u;
            unsigned mid  = lo_u + (span >> 1) + (span & 1u);
            float mf = mono_dec(mid);
            int c = 0;
#pragma unroll
            for (int j = 0; j < 64; ++j) c += (vals[j] >= mf) ? 1 : 0;
            c += __shfl_xor(c, 1);
            c += __shfl_xor(c, 2);
            if (active) {
                if (c == KKEEP)      { thr = mf; done = true; }
                else if (c >= KKEEP) lo_u = mid;
                else                 hi_u = mid - 1;
            }
        }
        if (!done) thr = mono_dec(lo_u);
    }

    // ---- masked softmax (unchanged) ----
    float rmx = -3e38f;
#pragma unroll
    for (int j = 0; j < 64; ++j) rmx = fmaxf(rmx, (vals[j] >= thr) ? vals[j] : -3e38f);
    rmx = fmaxf(rmx, __shfl_xor(rmx, 1));
    rmx = fmaxf(rmx, __shfl_xor(rmx, 2));
    float rsum = 0.f;
#pragma unroll
    for (int j = 0; j < 64; ++j) {
        float e = (vals[j] >= thr) ? __expf(vals[j] - rmx) : 0.f;
        vals[j] = e;
        rsum += e;
    }
    rsum += __shfl_xor(rsum, 1);
    rsum += __shfl_xor(rsum, 2);
    float rinv = 1.0f / rsum;
#pragma unroll
    for (int j = 0; j < 64; ++j) vals[j] *= rinv;

    // ---- PV via MFMA: 3 limb products (mh, hm, hh) ----
    const int sa2[3] = {1, 0, 0};
    const int sb2[3] = {0, 1, 0};
    f32x4 acc2[2][2] = {};
#pragma unroll
    for (int mc = 0; mc < 4; ++mc) {
        __syncthreads();                 // prev frag reads / st(vals) reads done
        // P limbs -> Qs (row rr, cols sub+4u of this chunk; swizzled singles)
#pragma unroll
        for (int u = 0; u < 16; ++u) {
            short ph, pm;
            split2(vals[mc * 16 + u], ph, pm);
            int ml   = sub + 4 * u;
            int slot = rr * 64 + (ml ^ ((rr & 7) << 3));
            Qs[slot]        = ph;
            Qs[4096 + slot] = pm;
        }
        // V^T limbs -> Ks, [d][m] stride 72 (m-contiguous b128 writes)
#pragma unroll
        for (int l = 0; l < 2; ++l) {
            int f  = l * 256 + t;
            int d  = f & 63;
            int mo = (f >> 6) * 8;       // f>>6 in 0..7 within each l
            s16x8 hv, mv;
#pragma unroll
            for (int i = 0; i < 8; ++i) {
                short vh, vm;
                split2(vb[(size_t)(mc * 64 + mo + i) * 1536 + d], vh, vm);
                hv[i] = vh; mv[i] = vm;
            }
            int o = d * 72 + mo;
            *(s16x8*)&Ks[o]        = hv;
            *(s16x8*)&Ks[4608 + o] = mv;
        }
        __syncthreads();

#pragma unroll
        for (int kk = 0; kk < 2; ++kk) {
            bf16x8 Pf[2][2], Vf[2][2];
#pragma unroll
            for (int s = 0; s < 2; ++s)
#pragma unroll
                for (int i = 0; i < 2; ++i) {
                    int pr = wr * 32 + i * 16 + fn;
                    int dr = wc * 32 + i * 16 + fn;
                    Pf[s][i] = *(const bf16x8*)&Qs[s * 4096 + pr * 64 + ((kk * 32 + fq) ^ ((pr & 7) << 3))];
                    Vf[s][i] = *(const bf16x8*)&Ks[s * 4608 + dr * 72 + kk * 32 + fq];
                }
#pragma unroll
            for (int p = 0; p < 3; ++p)
#pragma unroll
                for (int i = 0; i < 2; ++i)
#pragma unroll
                    for (int j = 0; j < 2; ++j)
                        acc2[i][j] = __builtin_amdgcn_mfma_f32_16x16x32_bf16(
                            Pf[sa2[p]][i], Vf[sb2[p]][j], acc2[i][j], 0, 0, 0);
        }
    }

    // ---- output: C/D layout col=lane&15, row=(lane>>4)*4+reg ----
#pragma unroll
    for (int j = 0; j < 2; ++j)
#pragma unroll
        for (int i = 0; i < 2; ++i)
#pragma unroll
            for (int r = 0; r < 4; ++r) {
                int row = rc * 64 + wr * 32 + i * 16 + g4 + r;
                int d   = wc * 32 + j * 16 + fn;
                qb[(size_t)row * 1536 + d] = acc2[i][j][r];
            }
}

// ---------------------------------------------------------------------------
extern "C" void kernel_launch(void* const* d_in, const int* in_sizes, int n_in,
                              void* d_out, int out_size, void* d_ws, size_t ws_size,
                              hipStream_t stream)
{
    (void)in_sizes; (void)n_in; (void)out_size; (void)ws_size;
    const float* x            = (const float*)d_in[0];
    const float* w_qkv        = (const float*)d_in[1];
    const float* w_out        = (const float*)d_in[2];
    const float* b_out        = (const float*)d_in[3];
    const float* local_bias   = (const float*)d_in[4];
    const float* global_param = (const float*)d_in[5];
    const float* gate         = (const float*)d_in[6];
    float* out = (float*)d_out;
    float* ws  = (float*)d_ws;

    // ws layout: qkv(192MB) | q_mean | k_mean | gbias | bf16 weight splits (~6MB)
    float* qkv    = ws;                                   // 32768*1536 f32
    float* q_mean = qkv + (size_t)32768 * 1536;           // 32*256*64
    float* k_mean = q_mean + (size_t)32 * 256 * 64;
    float* gb     = k_mean + (size_t)32 * 256 * 64;       // 32*256
    short* wsp    = (short*)(gb + 8192);
    short* WTh  = wsp;                    // w_qkv^T splits: [1536][512] bf16
    short* WTm  = WTh + (size_t)1536 * 512;
    short* WTl  = WTm + (size_t)1536 * 512;
    short* WoTh = WTl + (size_t)1536 * 512;   // w_out^T splits: [512][512]
    short* WoTm = WoTh + (size_t)512 * 512;
    short* WoTl = WoTm + (size_t)512 * 512;

    // 0) pre-split + transpose weights to bf16 limbs
    splitw_kernel<<<3072, 256, 0, stream>>>(w_qkv, 512, 1536, WTh, WTm, WTl);
    splitw_kernel<<<1024, 256, 0, stream>>>(w_out, 512, 512, WoTh, WoTm, WoTl);
    // 1) QKV projection via MFMA (6 limb-products for q/k cols, 3 for v cols)
    gemm_mfma<<<dim3(12, 256), 256, 0, stream>>>(x, 512, WTh, WTm, WTl,
                                                 nullptr, qkv, 1536, 1024);
    // 2) window means of q and k
    means_kernel<<<2048, 256, 0, stream>>>(qkv, q_mean, k_mean);
    // 3) global bias per (b,h,m)
    globalbias_kernel<<<32, 256, 0, stream>>>(q_mean, k_mean, global_param, gb);
    // 4) fused windowed attention; output in-place into q-slice of qkv
    attn_kernel<<<4096, 256, 0, stream>>>(qkv, local_bias, gb, gate);
    // 5) output projection via MFMA (3 limb-products) + bias
    gemm_mfma<<<dim3(4, 256), 256, 0, stream>>>(qkv, 1536, WoTh, WoTm, WoTl,
                                                b_out, out, 512, 0);
}

// Round 2
// 690.240 us; speedup vs baseline: 1.2418x; 1.0725x over previous
//
#include <hip/hip_runtime.h>

#define NN    8192
#define WSZ   256
#define KKEEP 179
#define SCALE 0.044194173824159216f   // 512^-0.5

#define APLANE ((size_t)32768 * 512)  // shorts per A limb plane
#define BPLANE ((size_t)1536 * 512)   // shorts per B (w_qkv^T) limb plane

typedef __attribute__((ext_vector_type(8))) __bf16 bf16x8;  // MFMA A/B frag (4 VGPRs)
typedef __attribute__((ext_vector_type(4))) short  s16x4;
typedef __attribute__((ext_vector_type(8))) short  s16x8;
typedef __attribute__((ext_vector_type(4))) float  f32x4;

// ---------------------------------------------------------------------------
// Dekker-style 3-way bf16 split: x ~= h + m + l  (repr. error ~2^-24 |x|).
// ---------------------------------------------------------------------------
struct Split3 { short h, m, l; };
__device__ __forceinline__ Split3 split3(float x)
{
    unsigned u  = __float_as_uint(x);
    unsigned hb = ((u + 0x7FFFu + ((u >> 16) & 1u)) >> 16) << 16;
    float r = x - __uint_as_float(hb);
    unsigned ur = __float_as_uint(r);
    unsigned mb = ((ur + 0x7FFFu + ((ur >> 16) & 1u)) >> 16) << 16;
    float r2 = r - __uint_as_float(mb);
    unsigned lr = __float_as_uint(r2);
    unsigned lb = (lr + 0x7FFFu + ((lr >> 16) & 1u)) >> 16;
    Split3 s;
    s.h = (short)(hb >> 16);
    s.m = (short)(mb >> 16);
    s.l = (short)(lb & 0xFFFFu);
    return s;
}

// 2-way split: x ~= h + m  (error ~2^-18 |x|) — for P (post-softmax) and V.
__device__ __forceinline__ void split2(float x, short& h, short& m)
{
    unsigned u  = __float_as_uint(x);
    unsigned hb = ((u + 0x7FFFu + ((u >> 16) & 1u)) >> 16) << 16;
    float r = x - __uint_as_float(hb);
    unsigned ur = __float_as_uint(r);
    unsigned mb = (ur + 0x7FFFu + ((ur >> 16) & 1u)) >> 16;
    h = (short)(hb >> 16);
    m = (short)(mb & 0xFFFFu);
}

// async 16B/lane global -> LDS (wave-uniform LDS base + lane*16 in HW)
__device__ __forceinline__ void async_copy16(short* dst_lds, const short* src)
{
    __builtin_amdgcn_global_load_lds(
        (const __attribute__((address_space(1))) void*)src,
        (__attribute__((address_space(3))) void*)dst_lds, 16, 0, 0);
}

// ---------------------------------------------------------------------------
// Pre-split + transpose a weight matrix W[K][N] fp32 -> h/m/l [N][K] bf16.
// (old flat layout — used for w_out always, and w_qkv in the fallback path)
// ---------------------------------------------------------------------------
__global__ __launch_bounds__(256) void splitw_kernel(const float* __restrict__ W,
                                                     int K, int N,
                                                     short* __restrict__ h,
                                                     short* __restrict__ m,
                                                     short* __restrict__ l)
{
    int idx = blockIdx.x * 256 + threadIdx.x;
    if (idx >= K * N) return;
    int k = idx / N, n = idx - k * N;
    Split3 s = split3(W[idx]);
    size_t o = (size_t)n * K + k;
    h[o] = s.h; m[o] = s.m; l[o] = s.l;
}

// ---------------------------------------------------------------------------
// Pre-split w_qkv into TILED + pre-swizzled limb planes for global_load_lds:
// plane[(cb*16+kt)*4096 + r*32 + ((s ^ ((r>>1)&3))<<3) + j]
//   cb = n/128, r = n%128, kt = k/32, s = (k%32)/8, j = k%8.
// One block per (cb,kt) tile; coalesced f32 reads via LDS transpose.
// ---------------------------------------------------------------------------
__global__ __launch_bounds__(256) void splitw_tiled(const float* __restrict__ W, int N,
                                                    short* __restrict__ Bh,
                                                    short* __restrict__ Bm,
                                                    short* __restrict__ Bl)
{
    __shared__ float raw[32 * 128];          // raw[k][n]
    const int cb = blockIdx.x >> 4;
    const int kt = blockIdx.x & 15;
    const int t  = threadIdx.x;

#pragma unroll
    for (int l = 0; l < 4; ++l) {
        int f  = l * 256 + t;                // 0..1023 float4 chunks
        int k  = f >> 5;                     // 0..31
        int nf = (f & 31) * 4;               // 0..124
        *(float4*)&raw[k * 128 + nf] =
            *(const float4*)&W[(size_t)(kt * 32 + k) * N + cb * 128 + nf];
    }
    __syncthreads();

    const int r  = t >> 1;                   // 0..127
    const int hf = t & 1;                    // which 16-short half
    const size_t base = ((size_t)(cb * 16 + kt) * 128 + r) * 32;
#pragma unroll
    for (int ss = 0; ss < 2; ++ss) {
        int s2 = hf * 2 + ss;                // slot 0..3
        s16x8 hv, mv, lv;
#pragma unroll
        for (int j = 0; j < 8; ++j) {
            Split3 sp = split3(raw[(s2 * 8 + j) * 128 + r]);
            hv[j] = sp.h; mv[j] = sp.m; lv[j] = sp.l;
        }
        size_t o = base + (size_t)((s2 ^ ((r >> 1) & 3)) << 3);
        *(s16x8*)&Bh[o] = hv;
        *(s16x8*)&Bm[o] = mv;
        *(s16x8*)&Bl[o] = lv;
    }
}

// ---------------------------------------------------------------------------
// Pre-split x[32768][512] -> 3 tiled+pre-swizzled limb planes (gload-ready).
// ---------------------------------------------------------------------------
__global__ __launch_bounds__(256) void splitA_kernel(const float* __restrict__ X,
                                                     short* __restrict__ Ah,
                                                     short* __restrict__ Am,
                                                     short* __restrict__ Al)
{
    int idx = blockIdx.x * 256 + threadIdx.x;     // 0..4194303
    int row = idx >> 7;                           // 0..32767
    int kf  = (idx & 127) << 2;                   // 0..508
    float4 a4 = *(const float4*)&X[((size_t)row << 9) + kf];
    int rb = row >> 7, r = row & 127;
    int kt = kf >> 5;
    int s  = (kf >> 3) & 3;
    int jj = kf & 7;                              // 0 or 4
    size_t o = ((size_t)(rb * 16 + kt) * 128 + r) * 32
             + (size_t)((s ^ ((r >> 1) & 3)) << 3) + jj;
    Split3 s0 = split3(a4.x), s1 = split3(a4.y), s2 = split3(a4.z), s3 = split3(a4.w);
    s16x4 hv, mv, lv;
    hv[0] = s0.h; hv[1] = s1.h; hv[2] = s2.h; hv[3] = s3.h;
    mv[0] = s0.m; mv[1] = s1.m; mv[2] = s2.m; mv[3] = s3.m;
    lv[0] = s0.l; lv[1] = s1.l; lv[2] = s2.l; lv[3] = s3.l;
    *(s16x4*)&Ah[o] = hv;
    *(s16x4*)&Am[o] = mv;
    *(s16x4*)&Al[o] = lv;
}

// ---------------------------------------------------------------------------
// QKV GEMM via global_load_lds: both A and B pre-split, pre-tiled,
// pre-swizzled.  128x128 tile, BK=32, single-buffered 48 KiB LDS
// (3 blocks/CU), 2-barrier m97 structure.  Zero staging VALU.
// Grid: dim3(12, 256); blockIdx.x<8 -> 6 limb products, else 3.
// ---------------------------------------------------------------------------
__global__ __launch_bounds__(256, 3) void gemm_gload(const short* __restrict__ Ab,
                                                     const short* __restrict__ Bb,
                                                     float* __restrict__ C)
{
    __shared__ __align__(16) short S[6 * 4096];   // planes: A h,m,l | B h,m,l

    const int t    = threadIdx.x;
    const int lane = t & 63;
    const int wave = t >> 6;
    const int wr   = wave >> 1;
    const int wc   = wave & 1;
    const int fn   = lane & 15;
    const int slot = lane >> 4;                   // frag k slot 0..3
    const int rowBlk = blockIdx.y;
    const int colBlk = blockIdx.x;
    const int pstart = (colBlk < 8) ? 0 : 3;

    const int sa[6] = {2, 0, 1, 1, 0, 0};
    const int sb[6] = {0, 2, 1, 0, 1, 0};

    f32x4 acc[4][4] = {};

    for (int kt = 0; kt < 16; ++kt) {
        __syncthreads();                          // prev tile's readers done
        // ---- stage: 48 x 1KB segments, 12 per wave, via global_load_lds ----
        const short* aT = Ab + ((size_t)(rowBlk * 16 + kt) << 12);
        const short* bT = Bb + ((size_t)(colBlk * 16 + kt) << 12);
#pragma unroll
        for (int c = 0; c < 12; ++c) {
            int g = wave * 12 + c;                // 0..47
            int p = g >> 3;                       // plane 0..5
            int q = g & 7;                        // segment within plane
            const short* src = (p < 3 ? aT + (size_t)p * APLANE
                                      : bT + (size_t)(p - 3) * BPLANE)
                             + q * 512 + lane * 8;
            async_copy16(&S[g * 512], src);
        }
        __syncthreads();                          // vmcnt(0) drain + barrier

        // ---- fragments (swizzled reads, 2-way = free) + MFMA ----
        bf16x8 Bf[3][4];
#pragma unroll
        for (int s = 0; s < 3; ++s)
#pragma unroll
            for (int j = 0; j < 4; ++j) {
                int rowb = wc * 64 + j * 16 + fn;
                Bf[s][j] = *(const bf16x8*)&S[(3 + s) * 4096 + rowb * 32
                                              + ((slot ^ ((rowb >> 1) & 3)) << 3)];
            }

#pragma unroll
        for (int i = 0; i < 4; ++i) {
            int rowa = wr * 64 + i * 16 + fn;
            bf16x8 Af[3];
#pragma unroll
            for (int s = 0; s < 3; ++s)
                Af[s] = *(const bf16x8*)&S[s * 4096 + rowa * 32
                                           + ((slot ^ ((rowa >> 1) & 3)) << 3)];
#pragma unroll
            for (int p = 0; p < 6; ++p) {
                if (p < pstart) continue;
#pragma unroll
                for (int j = 0; j < 4; ++j)
                    acc[i][j] = __builtin_amdgcn_mfma_f32_16x16x32_bf16(
                        Af[sa[p]], Bf[sb[p]][j], acc[i][j], 0, 0, 0);
            }
        }
    }

    const int crow0 = rowBlk * 128 + wr * 64 + (lane >> 4) * 4;
    const int ccol0 = colBlk * 128 + wc * 64 + fn;
#pragma unroll
    for (int j = 0; j < 4; ++j) {
        int col = ccol0 + j * 16;
#pragma unroll
        for (int i = 0; i < 4; ++i)
#pragma unroll
            for (int r = 0; r < 4; ++r)
                C[(size_t)(crow0 + i * 16 + r) * 1536 + col] = acc[i][j][r];
    }
}

// ---------------------------------------------------------------------------
// MFMA GEMM with in-kernel A split (fallback QKV path + out-projection).
// Changes vs prev round: pad 40 -> 32 shorts/row with XOR slot swizzle
// ((row>>1)&3) applied on write AND read (2-way conflicts = free), LDS
// 61440 -> 49152 (3 blocks/CU), launch_bounds min-waves 2 -> 3.
// ---------------------------------------------------------------------------
__global__ __launch_bounds__(256, 3) void gemm_mfma(const float* __restrict__ A, int lda,
                                                    const short* __restrict__ BTh,
                                                    const short* __restrict__ BTm,
                                                    const short* __restrict__ BTl,
                                                    const float* __restrict__ bias,
                                                    float* __restrict__ C, int ldc,
                                                    int qk_cols)
{
    __shared__ __align__(16) short Asm[3][128 * 32];   // [split][m][k] bf16, swizzled
    __shared__ __align__(16) short Bsm[3][128 * 32];   // [split][n][k] bf16, swizzled

    const int t       = threadIdx.x;
    const int lane    = t & 63;
    const int wave    = t >> 6;
    const int wr      = wave >> 1;
    const int wc      = wave & 1;
    const int rowBase = blockIdx.y * 128;
    const int colBase = blockIdx.x * 128;
    const int pstart  = (colBase < qk_cols) ? 0 : 3;

    const int sa[6] = {2, 0, 1, 1, 0, 0};
    const int sb[6] = {0, 2, 1, 0, 1, 0};

    const int fn   = lane & 15;
    const int slot = lane >> 4;

    f32x4 acc[4][4] = {};

    for (int ks = 0; ks < 512; ks += 32) {
        __syncthreads();

#pragma unroll
        for (int lo = 0; lo < 4; ++lo) {
            int idx = lo * 256 + t;
            int am  = idx >> 3;
            int af  = (idx & 7) * 4;
            float4 a4 = *(const float4*)&A[(size_t)(rowBase + am) * lda + ks + af];
            Split3 s0 = split3(a4.x);
            Split3 s1 = split3(a4.y);
            Split3 s2 = split3(a4.z);
            Split3 s3 = split3(a4.w);
            s16x4 hv, mv, lv;
            hv[0] = s0.h; hv[1] = s1.h; hv[2] = s2.h; hv[3] = s3.h;
            mv[0] = s0.m; mv[1] = s1.m; mv[2] = s2.m; mv[3] = s3.m;
            lv[0] = s0.l; lv[1] = s1.l; lv[2] = s2.l; lv[3] = s3.l;
            int o = am * 32 + (((af >> 3) ^ ((am >> 1) & 3)) << 3) + (af & 4);
            *(s16x4*)&Asm[0][o] = hv;
            *(s16x4*)&Asm[1][o] = mv;
            *(s16x4*)&Asm[2][o] = lv;
        }
#pragma unroll
        for (int lo = 0; lo < 2; ++lo) {
            int c = lo * 256 + t;
            int n = c >> 2;
            int q = (c & 3) * 8;
            size_t src = (size_t)(colBase + n) * 512 + ks + q;
            int o = n * 32 + (((q >> 3) ^ ((n >> 1) & 3)) << 3);
            *(s16x8*)&Bsm[0][o] = *(const s16x8*)&BTh[src];
            *(s16x8*)&Bsm[1][o] = *(const s16x8*)&BTm[src];
            *(s16x8*)&Bsm[2][o] = *(const s16x8*)&BTl[src];
        }
        __syncthreads();

        bf16x8 Bf[3][4];
#pragma unroll
        for (int s = 0; s < 3; ++s)
#pragma unroll
            for (int j = 0; j < 4; ++j) {
                int rowb = wc * 64 + j * 16 + fn;
                Bf[s][j] = *(const bf16x8*)&Bsm[s][rowb * 32
                                                   + ((slot ^ ((rowb >> 1) & 3)) << 3)];
            }

#pragma unroll
        for (int i = 0; i < 4; ++i) {
            int rowa = wr * 64 + i * 16 + fn;
            bf16x8 Af[3];
#pragma unroll
            for (int s = 0; s < 3; ++s)
                Af[s] = *(const bf16x8*)&Asm[s][rowa * 32
                                                + ((slot ^ ((rowa >> 1) & 3)) << 3)];
#pragma unroll
            for (int p = 0; p < 6; ++p) {
                if (p < pstart) continue;
#pragma unroll
                for (int j = 0; j < 4; ++j)
                    acc[i][j] = __builtin_amdgcn_mfma_f32_16x16x32_bf16(
                        Af[sa[p]], Bf[sb[p]][j], acc[i][j], 0, 0, 0);
            }
        }
    }

    const int crow0 = rowBase + wr * 64 + (lane >> 4) * 4;
    const int ccol0 = colBase + wc * 64 + fn;
#pragma unroll
    for (int j = 0; j < 4; ++j) {
        int col = ccol0 + j * 16;
        float bv = bias ? bias[col] : 0.0f;
#pragma unroll
        for (int i = 0; i < 4; ++i)
#pragma unroll
            for (int r = 0; r < 4; ++r)
                C[(size_t)(crow0 + i * 16 + r) * ldc + col] = acc[i][j][r] + bv;
    }
}

// ---------------------------------------------------------------------------
__global__ __launch_bounds__(256) void means_kernel(const float* __restrict__ qkv,
                                                    float* __restrict__ q_mean,
                                                    float* __restrict__ k_mean)
{
    int idx = blockIdx.x * 256 + threadIdx.x;
    int dd = idx & 63;
    int i  = (idx >> 6) & 255;
    int bh = idx >> 14;
    int b = bh >> 3, h = bh & 7;
    const float* base = qkv + (size_t)b * NN * 1536 + (size_t)h * 64 + dd;
    float qs = 0.f, ks = 0.f;
#pragma unroll
    for (int w = 0; w < 32; ++w) {
        size_t off = (size_t)(w * 256 + i) * 1536;
        qs += base[off];
        ks += base[off + 512];
    }
    q_mean[idx] = qs * 0.03125f;
    k_mean[idx] = ks * 0.03125f;
}

// ---------------------------------------------------------------------------
__global__ __launch_bounds__(256) void globalbias_kernel(const float* __restrict__ q_mean,
                                                         const float* __restrict__ k_mean,
                                                         const float* __restrict__ gp,
                                                         float* __restrict__ gbias)
{
    __shared__ float gq[32 * 64];
    const int bh = blockIdx.x;
    const int h  = bh & 7;
    const int t  = threadIdx.x;

#pragma unroll
    for (int e = 0; e < 8; ++e) {
        int idx = e * 256 + t;
        int g  = idx >> 6;
        int dd = idx & 63;
        const float* gpr = gp + (size_t)(h * 32 + g) * 256;
        const float* qm  = q_mean + (size_t)bh * 16384 + dd;
        float s = 0.f;
        for (int i = 0; i < 256; ++i) s += gpr[i] * qm[(size_t)i * 64];
        gq[idx] = s;
    }
    __syncthreads();

    const float* km = k_mean + (size_t)bh * 16384 + (size_t)t * 64;
    float4 kr[16];
#pragma unroll
    for (int j = 0; j < 16; ++j) kr[j] = *(const float4*)&km[4 * j];
    float acc = 0.f;
    for (int g = 0; g < 32; ++g) {
        const float* gqr = &gq[g * 64];
        float s = 0.f;
#pragma unroll
        for (int j = 0; j < 16; ++j) {
            float4 q4 = *(const float4*)&gqr[4 * j];
            s += q4.x * kr[j].x + q4.y * kr[j].y + q4.z * kr[j].z + q4.w * kr[j].w;
        }
        acc += s;
    }
    gbias[bh * 256 + t] = acc * SCALE * 0.03125f;
}

// ---------------------------------------------------------------------------
__device__ __forceinline__ unsigned mono_enc(float f) {
    unsigned u = __float_as_uint(f);
    return (u & 0x80000000u) ? ~u : (u | 0x80000000u);
}
__device__ __forceinline__ float mono_dec(unsigned e) {
    return (e & 0x80000000u) ? __uint_as_float(e ^ 0x80000000u)
                             : __uint_as_float(~e);
}

// ---------------------------------------------------------------------------
// Fused windowed attention (unchanged from previous round).
// ---------------------------------------------------------------------------
__global__ __launch_bounds__(256, 3) void attn_kernel(float* __restrict__ qkv,
                                                      const float* __restrict__ local_bias,
                                                      const float* __restrict__ gbias,
                                                      const float* __restrict__ gate)
{
    __shared__ __align__(16) short Qs[3 * 64 * 64];   // 24576 B
    __shared__ __align__(16) short Ks[3 * 64 * 64];   // 24576 B
    float* st = (float*)(void*)Ks;                    // [64][68] score tile (alias)

    const int t    = threadIdx.x;
    const int lane = t & 63;
    const int wave = t >> 6;
    const int wr   = wave >> 1;
    const int wc   = wave & 1;
    const int fn   = lane & 15;
    const int fq   = (lane >> 4) * 8;
    const int g4   = (lane >> 4) * 4;

    const int blk = blockIdx.x;
    const int rc  = blk & 3;
    const int w   = (blk >> 2) & 31;
    const int bh  = blk >> 7;
    const int h   = bh & 7;
    const int b   = bh >> 3;
    const float gateh = 1.0f / (1.0f + __expf(-gate[h]));

    const size_t tokBase = (size_t)b * NN + (size_t)w * WSZ;
    float* qb = qkv + tokBase * 1536 + h * 64;
    const float* kb = qb + 512;
    const float* vb = qb + 1024;

    const int rr = t >> 2, sub = t & 3;

    const int sa[6] = {2, 0, 1, 1, 0, 0};
    const int sb[6] = {0, 2, 1, 0, 1, 0};

#pragma unroll
    for (int l = 0; l < 4; ++l) {
        int f  = l * 256 + t;
        int r  = f >> 4;
        int dg = (f & 15) * 4;
        float4 a4 = *(const float4*)&qb[(size_t)(rc * 64 + r) * 1536 + dg];
        Split3 s0 = split3(a4.x), s1 = split3(a4.y), s2 = split3(a4.z), s3 = split3(a4.w);
        s16x4 hv, mv, lv;
        hv[0] = s0.h; hv[1] = s1.h; hv[2] = s2.h; hv[3] = s3.h;
        mv[0] = s0.m; mv[1] = s1.m; mv[2] = s2.m; mv[3] = s3.m;
        lv[0] = s0.l; lv[1] = s1.l; lv[2] = s2.l; lv[3] = s3.l;
        int o = r * 64 + (dg ^ ((r & 7) << 3));
        *(s16x4*)&Qs[o]        = hv;
        *(s16x4*)&Qs[4096 + o] = mv;
        *(s16x4*)&Qs[8192 + o] = lv;
    }

    float vals[64];
#pragma unroll
    for (int mc = 0; mc < 4; ++mc) {
        __syncthreads();
#pragma unroll
        for (int l = 0; l < 4; ++l) {
            int f  = l * 256 + t;
            int m  = f >> 4;
            int dg = (f & 15) * 4;
            float4 a4 = *(const float4*)&kb[(size_t)(mc * 64 + m) * 1536 + dg];
            Split3 s0 = split3(a4.x), s1 = split3(a4.y), s2 = split3(a4.z), s3 = split3(a4.w);
            s16x4 hv, mv, lv;
            hv[0] = s0.h; hv[1] = s1.h; hv[2] = s2.h; hv[3] = s3.h;
            mv[0] = s0.m; mv[1] = s1.m; mv[2] = s2.m; mv[3] = s3.m;
            lv[0] = s0.l; lv[1] = s1.l; lv[2] = s2.l; lv[3] = s3.l;
            int o = m * 64 + (dg ^ ((m & 7) << 3));
            *(s16x4*)&Ks[o]        = hv;
            *(s16x4*)&Ks[4096 + o] = mv;
            *(s16x4*)&Ks[8192 + o] = lv;
        }
        __syncthreads();

        f32x4 acc[2][2] = {};
#pragma unroll
        for (int kk = 0; kk < 2; ++kk) {
            bf16x8 Af[3][2], Bf[3][2];
#pragma unroll
            for (int s = 0; s < 3; ++s)
#pragma unroll
                for (int i = 0; i < 2; ++i) {
                    int ar = wr * 32 + i * 16 + fn;
                    int bc = wc * 32 + i * 16 + fn;
                    Af[s][i] = *(const bf16x8*)&Qs[s * 4096 + ar * 64 + ((kk * 32 + fq) ^ ((ar & 7) << 3))];
                    Bf[s][i] = *(const bf16x8*)&Ks[s * 4096 + bc * 64 + ((kk * 32 + fq) ^ ((bc & 7) << 3))];
                }
#pragma unroll
            for (int p = 0; p < 6; ++p)
#pragma unroll
                for (int i = 0; i < 2; ++i)
#pragma unroll
                    for (int j = 0; j < 2; ++j)
                        acc[i][j] = __builtin_amdgcn_mfma_f32_16x16x32_bf16(
                            Af[sa[p]][i], Bf[sb[p]][j], acc[i][j], 0, 0, 0);
        }
        __syncthreads();

#pragma unroll
        for (int j = 0; j < 2; ++j) {
            int cl = wc * 32 + j * 16 + fn;
            int cf = mc * 64 + cl;
            float gb = gateh * gbias[bh * 256 + cf];
#pragma unroll
            for (int i = 0; i < 2; ++i)
#pragma unroll
                for (int r = 0; r < 4; ++r) {
                    int rl = wr * 32 + i * 16 + g4 + r;
                    st[rl * 68 + cl] = acc[i][j][r] * SCALE
                        + local_bias[((size_t)h * 256 + rc * 64 + rl) * 256 + cf] + gb;
                }
        }
        __syncthreads();
#pragma unroll
        for (int j = 0; j < 16; ++j)
            vals[mc * 16 + j] = st[rr * 68 + sub + 4 * j];
    }

    float rmin = vals[0], rmax = vals[0];
#pragma unroll
    for (int j = 1; j < 64; ++j) {
        rmin = fminf(rmin, vals[j]);
        rmax = fmaxf(rmax, vals[j]);
    }
    rmin = fminf(rmin, __shfl_xor(rmin, 1)); rmin = fminf(rmin, __shfl_xor(rmin, 2));
    rmax = fmaxf(rmax, __shfl_xor(rmax, 1)); rmax = fmaxf(rmax, __shfl_xor(rmax, 2));

    float flo = rmin, fhi = rmax;
    float thr = 0.f;
    bool  done = false;
    for (int it = 0; it < 16; ++it) {
        if (__all(done ? 1 : 0)) break;
        float mf = 0.5f * (flo + fhi);
        int c = 0;
#pragma unroll
        for (int j = 0; j < 64; ++j) c += (vals[j] >= mf) ? 1 : 0;
        c += __shfl_xor(c, 1);
        c += __shfl_xor(c, 2);
        if (!done) {
            if (c == KKEEP)      { thr = mf; done = true; }
            else if (c > KKEEP)  flo = mf;
            else                 fhi = mf;
        }
    }
    if (__any(done ? 0 : 1)) {
        unsigned lo_u = mono_enc(flo), hi_u = mono_enc(fhi);
        for (int it = 0; it < 34; ++it) {
            bool active = (!done) && (lo_u < hi_u);
            if (!__any(active ? 1 : 0)) break;
            unsigned span = hi_u - lo_u;
            unsigned mid  = lo_u + (span >> 1) + (span & 1u);
            float mf = mono_dec(mid);
            int c = 0;
#pragma unroll
            for (int j = 0; j < 64; ++j) c += (vals[j] >= mf) ? 1 : 0;
            c += __shfl_xor(c, 1);
            c += __shfl_xor(c, 2);
            if (active) {
                if (c == KKEEP)      { thr = mf; done = true; }
                else if (c >= KKEEP) lo_u = mid;
                else                 hi_u = mid - 1;
            }
        }
        if (!done) thr = mono_dec(lo_u);
    }

    float rmx = -3e38f;
#pragma unroll
    for (int j = 0; j < 64; ++j) rmx = fmaxf(rmx, (vals[j] >= thr) ? vals[j] : -3e38f);
    rmx = fmaxf(rmx, __shfl_xor(rmx, 1));
    rmx = fmaxf(rmx, __shfl_xor(rmx, 2));
    float rsum = 0.f;
#pragma unroll
    for (int j = 0; j < 64; ++j) {
        float e = (vals[j] >= thr) ? __expf(vals[j] - rmx) : 0.f;
        vals[j] = e;
        rsum += e;
    }
    rsum += __shfl_xor(rsum, 1);
    rsum += __shfl_xor(rsum, 2);
    float rinv = 1.0f / rsum;
#pragma unroll
    for (int j = 0; j < 64; ++j) vals[j] *= rinv;

    const int sa2[3] = {1, 0, 0};
    const int sb2[3] = {0, 1, 0};
    f32x4 acc2[2][2] = {};
#pragma unroll
    for (int mc = 0; mc < 4; ++mc) {
        __syncthreads();
#pragma unroll
        for (int u = 0; u < 16; ++u) {
            short ph, pm;
            split2(vals[mc * 16 + u], ph, pm);
            int ml   = sub + 4 * u;
            int slot = rr * 64 + (ml ^ ((rr & 7) << 3));
            Qs[slot]        = ph;
            Qs[4096 + slot] = pm;
        }
#pragma unroll
        for (int l = 0; l < 2; ++l) {
            int f  = l * 256 + t;
            int d  = f & 63;
            int mo = (f >> 6) * 8;
            s16x8 hv, mv;
#pragma unroll
            for (int i = 0; i < 8; ++i) {
                short vh, vm;
                split2(vb[(size_t)(mc * 64 + mo + i) * 1536 + d], vh, vm);
                hv[i] = vh; mv[i] = vm;
            }
            int o = d * 72 + mo;
            *(s16x8*)&Ks[o]        = hv;
            *(s16x8*)&Ks[4608 + o] = mv;
        }
        __syncthreads();

#pragma unroll
        for (int kk = 0; kk < 2; ++kk) {
            bf16x8 Pf[2][2], Vf[2][2];
#pragma unroll
            for (int s = 0; s < 2; ++s)
#pragma unroll
                for (int i = 0; i < 2; ++i) {
                    int pr = wr * 32 + i * 16 + fn;
                    int dr = wc * 32 + i * 16 + fn;
                    Pf[s][i] = *(const bf16x8*)&Qs[s * 4096 + pr * 64 + ((kk * 32 + fq) ^ ((pr & 7) << 3))];
                    Vf[s][i] = *(const bf16x8*)&Ks[s * 4608 + dr * 72 + kk * 32 + fq];
                }
#pragma unroll
            for (int p = 0; p < 3; ++p)
#pragma unroll
                for (int i = 0; i < 2; ++i)
#pragma unroll
                    for (int j = 0; j < 2; ++j)
                        acc2[i][j] = __builtin_amdgcn_mfma_f32_16x16x32_bf16(
                            Pf[sa2[p]][i], Vf[sb2[p]][j], acc2[i][j], 0, 0, 0);
        }
    }

#pragma unroll
    for (int j = 0; j < 2; ++j)
#pragma unroll
        for (int i = 0; i < 2; ++i)
#pragma unroll
            for (int r = 0; r < 4; ++r) {
                int row = rc * 64 + wr * 32 + i * 16 + g4 + r;
                int d   = wc * 32 + j * 16 + fn;
                qb[(size_t)row * 1536 + d] = acc2[i][j][r];
            }
}

// ---------------------------------------------------------------------------
extern "C" void kernel_launch(void* const* d_in, const int* in_sizes, int n_in,
                              void* d_out, int out_size, void* d_ws, size_t ws_size,
                              hipStream_t stream)
{
    (void)in_sizes; (void)n_in; (void)out_size;
    const float* x            = (const float*)d_in[0];
    const float* w_qkv        = (const float*)d_in[1];
    const float* w_out        = (const float*)d_in[2];
    const float* b_out        = (const float*)d_in[3];
    const float* local_bias   = (const float*)d_in[4];
    const float* global_param = (const float*)d_in[5];
    const float* gate         = (const float*)d_in[6];
    float* out = (float*)d_out;
    float* ws  = (float*)d_ws;

    // ws layout: qkv(192MB) | q_mean | k_mean | gbias | w_out splits |
    //            w_qkv splits (old OR tiled layout, same size) | A limb planes
    float* qkv    = ws;                                   // 32768*1536 f32
    float* q_mean = qkv + (size_t)32768 * 1536;           // 32*256*64
    float* k_mean = q_mean + (size_t)32 * 256 * 64;
    float* gb     = k_mean + (size_t)32 * 256 * 64;       // 32*256
    short* wsp    = (short*)(gb + 8192);
    short* WoTh = wsp;                        // w_out^T splits: [512][512] (old layout)
    short* WoTm = WoTh + (size_t)512 * 512;
    short* WoTl = WoTm + (size_t)512 * 512;
    short* WqB  = WoTl + (size_t)512 * 512;   // w_qkv splits: 3 planes of 1536*512
    short* Almb = WqB + 3 * BPLANE;           // x limb planes: 3 * 32768*512

    size_t need = (size_t)((char*)(Almb + 3 * APLANE) - (char*)ws);
    bool pre = ws_size >= need;

    // 0) w_out splits (old flat layout) — always
    splitw_kernel<<<1024, 256, 0, stream>>>(w_out, 512, 512, WoTh, WoTm, WoTl);

    if (pre) {
        // tiled+swizzled limb planes for gload path
        splitw_tiled<<<192, 256, 0, stream>>>(w_qkv, 1536,
                                              WqB, WqB + BPLANE, WqB + 2 * BPLANE);
        splitA_kernel<<<16384, 256, 0, stream>>>(x, Almb, Almb + APLANE, Almb + 2 * APLANE);
        gemm_gload<<<dim3(12, 256), 256, 0, stream>>>(Almb, WqB, qkv);
    } else {
        splitw_kernel<<<3072, 256, 0, stream>>>(w_qkv, 512, 1536,
                                                WqB, WqB + BPLANE, WqB + 2 * BPLANE);
        gemm_mfma<<<dim3(12, 256), 256, 0, stream>>>(x, 512, WqB, WqB + BPLANE,
                                                     WqB + 2 * BPLANE,
                                                     nullptr, qkv, 1536, 1024);
    }

    // 2) window means of q and k
    means_kernel<<<2048, 256, 0, stream>>>(qkv, q_mean, k_mean);
    // 3) global bias per (b,h,m)
    globalbias_kernel<<<32, 256, 0, stream>>>(q_mean, k_mean, global_param, gb);
    // 4) fused windowed attention; output in-place into q-slice of qkv
    attn_kernel<<<4096, 256, 0, stream>>>(qkv, local_bias, gb, gate);
    // 5) output projection via MFMA (3 limb-products) + bias
    gemm_mfma<<<dim3(4, 256), 256, 0, stream>>>(qkv, 1536, WoTh, WoTm, WoTl,
                                                b_out, out, 512, 0);
}